// Round 6
// baseline (290.966 us; speedup 1.0000x reference)
//
#include <hip/hip_runtime.h>
#include <hip/hip_bf16.h>
#include <math.h>

#define TT 4096   // tokens (B*S)
#define HH 1024   // hidden
#define EE 8      // experts
#define II 1024   // intermediate

typedef __bf16 bf16x8 __attribute__((ext_vector_type(8)));
typedef float  floatx4 __attribute__((ext_vector_type(4)));
typedef __hip_bfloat16 bf16;

// async global->LDS, 16B per lane. LDS dest is wave-uniform base + lane*16;
// global address is per-lane (gather allowed).
__device__ __forceinline__ void async_copy16(const void* g, void* s) {
  __builtin_amdgcn_global_load_lds((__attribute__((address_space(1))) void*)g,
                                   (__attribute__((address_space(3))) void*)s,
                                   16, 0, 0);
}

// R14: transpose ELIMINATED. prep's weight pass is now a pure streaming
// fp32->bf16 convert (same layout); the k-major->n-major transpose moved into
// the GEMMs' B-staging: reg-staged row loads (8B/lane) + in-reg 8kx4n
// micro-transpose + swizzled ds_write_b128 (write-side swizzle legal with
// reg-staging). B regs double-buffered: loads for step k+1 issued before
// MFMA of step k. R4's atomicAdd combine REVERTED (cost +19us): gemm2 writes
// Obuf, separate combine kernel restored.

// B-staging macros: bsrc = weight base + ibase (col offset), row stride 1024.
#define LOADB(v, kk) do { \
  _Pragma("unroll") \
  for (int j = 0; j < 8; j++) \
    v[j] = *(const uint2*)(bsrc + (size_t)((kk) + bo * 8 + j) * 1024); \
} while (0)

// component c of each ushort4 row -> one 16B LDS write (8 k-contig bf16)
#define STOREB(v) do { \
  _Pragma("unroll") \
  for (int c = 0; c < 4; c++) { \
    const int hs = (c & 1) * 16; \
    uint q0 = (c >> 1) ? v[0].y : v[0].x, q1 = (c >> 1) ? v[1].y : v[1].x; \
    uint q2 = (c >> 1) ? v[2].y : v[2].x, q3 = (c >> 1) ? v[3].y : v[3].x; \
    uint q4 = (c >> 1) ? v[4].y : v[4].x, q5 = (c >> 1) ? v[5].y : v[5].x; \
    uint q6 = (c >> 1) ? v[6].y : v[6].x, q7 = (c >> 1) ? v[7].y : v[7].x; \
    uint4 pk; \
    pk.x = ((q0 >> hs) & 0xffffu) | (((q1 >> hs) & 0xffffu) << 16); \
    pk.y = ((q2 >> hs) & 0xffffu) | (((q3 >> hs) & 0xffffu) << 16); \
    pk.z = ((q4 >> hs) & 0xffffu) | (((q5 >> hs) & 0xffffu) << 16); \
    pk.w = ((q6 >> hs) & 0xffffu) | (((q7 >> hs) & 0xffffu) << 16); \
    *(uint4*)(Bs + bw[c]) = pk; \
  } \
} while (0)

// ---------------- prep: convert-copy weights (z<24) | router (z>=24) ----------------
__global__ __launch_bounds__(256) void prep_kernel(
    const float* __restrict__ Wg, const float* __restrict__ Wu, const float* __restrict__ Wd,
    bf16* __restrict__ wgb, bf16* __restrict__ wub, bf16* __restrict__ wdb,
    const float* __restrict__ x, const float* __restrict__ Wr,
    bf16* __restrict__ xb, int* __restrict__ pair, float2* __restrict__ w2,
    float* __restrict__ impPart, int* __restrict__ cnt, int* __restrict__ done)
{
  const int tid = threadIdx.x;
  if (blockIdx.z < 24) {
    // ---- streaming fp32->bf16 convert, layout preserved ----
    const int zi = blockIdx.z >> 3, e = blockIdx.z & 7;
    const float* s = (zi == 0 ? Wg : zi == 1 ? Wu : Wd) + (size_t)e * 1024 * 1024;
    bf16* d = (zi == 0 ? wgb : zi == 1 ? wub : wdb) + (size_t)e * 1024 * 1024;
    const int base = (blockIdx.y * 16 + blockIdx.x) * 8192;
    #pragma unroll
    for (int i = 0; i < 8; i++) {
      int idx = base + tid * 4 + i * 1024;
      float4 v = *(const float4*)(s + idx);
      bf16 t4[4] = {__float2bfloat16(v.x), __float2bfloat16(v.y),
                    __float2bfloat16(v.z), __float2bfloat16(v.w)};
      *(float2*)(d + idx) = *(float2*)t4;     // 8B store
    }
  } else {
    // ---- router path: 1024 blocks (z=24..31, 128/plane), 4 tokens/block ----
    __shared__ float simp[8];
    const int rb = (blockIdx.z - 24) * 128 + blockIdx.y * 16 + blockIdx.x;
    if (tid < 8) simp[tid] = 0.f;
    if (rb == 0) {                                     // replaces hipMemsetAsync(cnt)
      if (tid < 8) cnt[tid] = 0;
      else if (tid == 8) *done = 0;
    }
    __syncthreads();

    const int w = tid >> 6, lane = tid & 63;
    const int t = rb * 4 + w;
    const float* xr = x + (size_t)t * HH;
    float acc[8] = {0.f,0.f,0.f,0.f,0.f,0.f,0.f,0.f};
    #pragma unroll
    for (int i = 0; i < 16; i++) {
      int h = lane + i * 64;
      float xv = xr[h];
      xb[(size_t)t * HH + h] = __float2bfloat16(xv);
      const float4* wr = (const float4*)(Wr + h * 8);
      float4 a = wr[0], b = wr[1];
      acc[0] += xv * a.x; acc[1] += xv * a.y; acc[2] += xv * a.z; acc[3] += xv * a.w;
      acc[4] += xv * b.x; acc[5] += xv * b.y; acc[6] += xv * b.z; acc[7] += xv * b.w;
    }
    #pragma unroll
    for (int e = 0; e < 8; e++) {
      #pragma unroll
      for (int off = 32; off > 0; off >>= 1)
        acc[e] += __shfl_xor(acc[e], off);
    }
    if (lane == 0) {
      int i0 = 0;
      #pragma unroll
      for (int e = 1; e < 8; e++) if (acc[e] > acc[i0]) i0 = e;   // lowest index wins ties
      int i1 = (i0 == 0) ? 1 : 0;
      #pragma unroll
      for (int e = 0; e < 8; e++) if (e != i0 && acc[e] > acc[i1]) i1 = e;
      float mx = acc[i0];
      float pe[8]; float s = 0.f;
      #pragma unroll
      for (int e = 0; e < 8; e++) { pe[e] = __expf(acc[e] - mx); s += pe[e]; }
      float inv = 1.f / s;
      #pragma unroll
      for (int e = 0; e < 8; e++) atomicAdd(simp + e, pe[e] * inv);   // LDS atomic
      float p0 = pe[i0] * inv, p1 = pe[i1] * inv;
      float wn2 = 1.f / (p0 + p1);
      pair[t] = i0 | (i1 << 8);
      w2[t] = make_float2(p0 * wn2, p1 * wn2);
    }
    __syncthreads();
    if (tid < 8) impPart[rb * 8 + tid] = simp[tid];
  }
}

// ---------------- scatter + fused finalize (last-block) ----------------
__global__ __launch_bounds__(256) void scatter_kernel(
    const int* __restrict__ pair, const float2* __restrict__ w2,
    int* __restrict__ cnt, int* __restrict__ tok_list, int2* __restrict__ slot2,
    const float* __restrict__ impPart, int* __restrict__ done,
    int* __restrict__ offs, float* __restrict__ aux_out)
{
  __shared__ int lcnt[8];
  __shared__ int lbase[8];
  __shared__ float part[256];
  __shared__ int scnt[8];
  __shared__ int lastFlag;
  const int tid = threadIdx.x;
  const int t = blockIdx.x * 256 + tid;
  if (tid < 8) lcnt[tid] = 0;
  __syncthreads();
  int pr = pair[t];
  int e0 = pr & 0xff, e1 = pr >> 8;
  int lp0 = atomicAdd(lcnt + e0, 1);
  int lp1 = atomicAdd(lcnt + e1, 1);
  __syncthreads();
  if (tid < 8) lbase[tid] = atomicAdd(cnt + tid, lcnt[tid]);   // 8 global atomics per block
  __syncthreads();
  int p0 = lbase[e0] + lp0, p1 = lbase[e1] + lp1;
  tok_list[e0 * TT + p0] = t;
  tok_list[e1 * TT + p1] = t;
  slot2[t] = make_int2((e0 << 12) | p0, (e1 << 12) | p1);

  // ---- fused finalize: last block reduces impPart, prefix offsets, aux ----
  __threadfence();
  __syncthreads();
  if (tid == 0) lastFlag = (atomicAdd(done, 1) == (int)gridDim.x - 1);
  __syncthreads();
  if (!lastFlag) return;
  __threadfence();                                   // acquire
  if (tid < 8) scnt[tid] = atomicAdd(cnt + tid, 0);  // coherent cross-XCD read
  const int e = tid & 7, r = tid >> 3;               // 32 chunks x 8 experts
  float s = 0.f;
  for (int i = r; i < 1024; i += 32) s += impPart[i * 8 + e];  // prep output: plain read OK
  part[tid] = s;
  __syncthreads();
  if (tid == 0) {
    float impf[8];
    #pragma unroll
    for (int e2 = 0; e2 < 8; e2++) {
      float ss = 0.f;
      #pragma unroll
      for (int j = 0; j < 32; j++) ss += part[j * 8 + e2];
      impf[e2] = ss;
    }
    int o = 0; float sl = 0.f;
    for (int e2 = 0; e2 < 8; e2++) { offs[e2] = o; o += scnt[e2]; sl += (float)scnt[e2] * impf[e2]; }
    aux_out[0] = (float)EE * 0.01f * sl / ((float)TT * (float)TT);
  }
}

// ---------------- gemm1: inter = silu(A@Wg) * (A@Wu); B staged w/ micro-transpose ----------------
// 128M x 128N tile over logical N=2048 interleave (n=(i>>4)*32+mat*16+(i&15)),
// BK=64; A via global_load_lds from xb; B: 8B row loads from UNtransposed
// wgb/wub + in-reg 8kx4n transpose + swizzled ds_write_b128, double-buffered.
__global__ __launch_bounds__(256) void gemm1_kernel(
    const bf16* __restrict__ xb, const bf16* __restrict__ wgb, const bf16* __restrict__ wub,
    const int* __restrict__ cnt, const int* __restrict__ offs,
    const int* __restrict__ tok_list, bf16* __restrict__ inter)
{
  const int flat = blockIdx.x + 16 * (blockIdx.y + 32 * blockIdx.z);
  const int work = (flat & 7) * 512 + (flat >> 3);
  const int e = work >> 9;
  const int M = cnt[e];
  const int m0 = ((work >> 4) & 31) * 128;
  if (m0 >= M) return;
  const int n0 = (work & 15) * 128;
  const int off = offs[e];

  __shared__ alignas(16) bf16 As[128 * 64];   // 16 KB
  __shared__ alignas(16) bf16 Bs[128 * 64];   // 16 KB
  __shared__ int sTok[128];

  const int tid = threadIdx.x;
  if (tid < 128) {
    int p = m0 + tid;
    sTok[tid] = tok_list[e * TT + (p < M ? p : M - 1)];
  }

  const int w = tid >> 6, lane = tid & 63;
  const int quad = lane >> 4, l16 = lane & 15;
  const int srow = lane >> 3, schunk = lane & 7;   // A staging: 8 rows x 8 chunks/issue
  const int wm = (w & 1) * 64, wn = (w >> 1) * 64;

  // B-staging thread mapping: 32 n-groups of 4 x 8 k-octets
  const int bg = tid & 31, bo = tid >> 5;
  const int nl = bg * 4;
  const int nglob = n0 + nl;
  const int ibase = ((nglob >> 5) << 4) + (nglob & 15);      // source col in Wg/Wu
  const bf16* bsrc = (((nglob >> 4) & 1) ? wub : wgb) + (size_t)e * 1024 * 1024 + ibase;
  int bw[4];
  #pragma unroll
  for (int c = 0; c < 4; c++) {
    int n = nl + c;
    bw[c] = n * 64 + ((bo ^ (n & 7)) << 3);    // swizzled: chunk bo of row n
  }

  floatx4 zero4 = {0.f, 0.f, 0.f, 0.f};
  floatx4 acc[4][4];
  #pragma unroll
  for (int mi = 0; mi < 4; mi++)
    #pragma unroll
    for (int ni = 0; ni < 4; ni++) acc[mi][ni] = zero4;

  __syncthreads();  // sTok visible

  // A staging: 16 issues, 4 per wave; k-invariant pointers
  const bf16* srcA[4]; bf16* dstA[4];
  #pragma unroll
  for (int i = 0; i < 4; i++) {
    int q = w + 4 * i, r = q * 8 + srow;
    int col = ((schunk ^ (r & 7)) << 3);
    srcA[i] = xb + (size_t)sTok[r] * HH + col;
    dstA[i] = As + q * 512;
  }
  // k-invariant swizzled LDS read offsets
  int offA[4][2], offB[4][2];
  #pragma unroll
  for (int mi = 0; mi < 4; mi++) {
    int r = wm + mi * 16 + l16;
    #pragma unroll
    for (int h = 0; h < 2; h++)
      offA[mi][h] = r * 64 + (((h * 4 + quad) ^ (r & 7)) << 3);
  }
  #pragma unroll
  for (int ni = 0; ni < 4; ni++) {
    int r = wn + ni * 16 + l16;
    #pragma unroll
    for (int h = 0; h < 2; h++)
      offB[ni][h] = r * 64 + (((h * 4 + quad) ^ (r & 7)) << 3);
  }

#define G1_MFMA() do { \
    bf16x8 af[4][2]; \
    _Pragma("unroll") \
    for (int mi = 0; mi < 4; mi++) { \
      af[mi][0] = *(const bf16x8*)(As + offA[mi][0]); \
      af[mi][1] = *(const bf16x8*)(As + offA[mi][1]); \
    } \
    _Pragma("unroll") \
    for (int ni = 0; ni < 4; ni++) { \
      bf16x8 b0 = *(const bf16x8*)(Bs + offB[ni][0]); \
      bf16x8 b1 = *(const bf16x8*)(Bs + offB[ni][1]); \
      _Pragma("unroll") \
      for (int mi = 0; mi < 4; mi++) { \
        acc[mi][ni] = __builtin_amdgcn_mfma_f32_16x16x32_bf16(af[mi][0], b0, acc[mi][ni], 0, 0, 0); \
        acc[mi][ni] = __builtin_amdgcn_mfma_f32_16x16x32_bf16(af[mi][1], b1, acc[mi][ni], 0, 0, 0); \
      } \
    } \
  } while (0)

  uint2 vA[8], vB[8];
  LOADB(vA, 0);
  for (int k0 = 0; k0 < HH; k0 += 128) {
    // step 0: consume vA, prefetch vB@k0+64
    if (k0) __syncthreads();
    #pragma unroll
    for (int i = 0; i < 4; i++) { async_copy16(srcA[i], dstA[i]); srcA[i] += 64; }
    STOREB(vA);
    LOADB(vB, k0 + 64);
    __syncthreads();
    G1_MFMA();
    // step 1: consume vB, prefetch vA@k0+128
    __syncthreads();
    #pragma unroll
    for (int i = 0; i < 4; i++) { async_copy16(srcA[i], dstA[i]); srcA[i] += 64; }
    STOREB(vB);
    if (k0 + 128 < HH) LOADB(vA, k0 + 128);
    __syncthreads();
    G1_MFMA();
  }

  // epilogue: pair frags (2*pr = g, 2*pr+1 = u); i = (n0+wn)/2 + pr*16 + l16
  #pragma unroll
  for (int mi = 0; mi < 4; mi++)
    #pragma unroll
    for (int pr = 0; pr < 2; pr++) {
      int icol = ((n0 + wn) >> 1) + pr * 16 + l16;
      #pragma unroll
      for (int r = 0; r < 4; r++) {
        int row = wm + mi * 16 + quad * 4 + r;
        int p = m0 + row;
        if (p < M) {
          float gv = acc[mi][2 * pr][r], uv = acc[mi][2 * pr + 1][r];
          float val = gv / (1.f + __expf(-gv)) * uv;
          inter[(size_t)(off + p) * II + icol] = __float2bfloat16(val);
        }
      }
    }
}

// ---------------- gemm2: Obuf[slot] = inter @ Wd; B staged w/ micro-transpose ----------------
// B[n=h][k=i] = Wd[e][i][h] (untransposed): same reg-staging as gemm1, direct n map.
__global__ __launch_bounds__(256) void gemm2_kernel(
    const bf16* __restrict__ inter, const bf16* __restrict__ wdb,
    const int* __restrict__ cnt, const int* __restrict__ offs,
    bf16* __restrict__ Obuf)
{
  const int flat = blockIdx.x + 8 * (blockIdx.y + 32 * blockIdx.z);
  const int work = (flat & 7) * 256 + (flat >> 3);
  const int e = work >> 8;
  const int M = cnt[e];
  const int m0 = ((work >> 3) & 31) * 128;
  if (m0 >= M) return;
  const int n0 = (work & 7) * 128;
  const int off = offs[e];

  __shared__ alignas(16) bf16 As[128 * 64];   // 16 KB
  __shared__ alignas(16) bf16 Bs[128 * 64];   // 16 KB

  const int tid = threadIdx.x;
  const int w = tid >> 6, lane = tid & 63;
  const int quad = lane >> 4, l16 = lane & 15;
  const int srow = lane >> 3, schunk = lane & 7;
  const int wm = (w & 1) * 64, wn = (w >> 1) * 64;

  const int bg = tid & 31, bo = tid >> 5;
  const int nl = bg * 4;
  const bf16* bsrc = wdb + (size_t)e * 1024 * 1024 + (n0 + nl);
  int bw[4];
  #pragma unroll
  for (int c = 0; c < 4; c++) {
    int n = nl + c;
    bw[c] = n * 64 + ((bo ^ (n & 7)) << 3);
  }

  floatx4 zero4 = {0.f, 0.f, 0.f, 0.f};
  floatx4 acc[4][4];
  #pragma unroll
  for (int mi = 0; mi < 4; mi++)
    #pragma unroll
    for (int ni = 0; ni < 4; ni++) acc[mi][ni] = zero4;

  // A staging: 16 issues, 4 per wave
  const bf16* srcA[4]; bf16* dstA[4];
  #pragma unroll
  for (int i = 0; i < 4; i++) {
    int q = w + 4 * i, r = q * 8 + srow;
    int col = ((schunk ^ (r & 7)) << 3);
    int p = m0 + r; int pc = p < M ? p : M - 1;
    srcA[i] = inter + (size_t)(off + pc) * II + col;
    dstA[i] = As + q * 512;
  }
  int offA[4][2], offB[4][2];
  #pragma unroll
  for (int mi = 0; mi < 4; mi++) {
    int r = wm + mi * 16 + l16;
    #pragma unroll
    for (int h = 0; h < 2; h++)
      offA[mi][h] = r * 64 + (((h * 4 + quad) ^ (r & 7)) << 3);
  }
  #pragma unroll
  for (int ni = 0; ni < 4; ni++) {
    int r = wn + ni * 16 + l16;
    #pragma unroll
    for (int h = 0; h < 2; h++)
      offB[ni][h] = r * 64 + (((h * 4 + quad) ^ (r & 7)) << 3);
  }

  uint2 vA[8], vB[8];
  LOADB(vA, 0);
  for (int k0 = 0; k0 < II; k0 += 128) {
    if (k0) __syncthreads();
    #pragma unroll
    for (int i = 0; i < 4; i++) { async_copy16(srcA[i], dstA[i]); srcA[i] += 64; }
    STOREB(vA);
    LOADB(vB, k0 + 64);
    __syncthreads();
    G1_MFMA();
    __syncthreads();
    #pragma unroll
    for (int i = 0; i < 4; i++) { async_copy16(srcA[i], dstA[i]); srcA[i] += 64; }
    STOREB(vB);
    if (k0 + 128 < II) LOADB(vA, k0 + 128);
    __syncthreads();
    G1_MFMA();
  }

  #pragma unroll
  for (int mi = 0; mi < 4; mi++)
    #pragma unroll
    for (int ni = 0; ni < 4; ni++) {
      #pragma unroll
      for (int r = 0; r < 4; r++) {
        int row = wm + mi * 16 + quad * 4 + r;
        int p = m0 + row;
        if (p < M)
          Obuf[(size_t)(off + p) * HH + (n0 + wn + ni * 16 + l16)] = __float2bfloat16(acc[mi][ni][r]);
      }
    }
}

// ---------------- combine: out[t] = g0*Obuf[slot0] + g1*Obuf[slot1] ----------------
__global__ __launch_bounds__(256) void combine_kernel(
    const bf16* __restrict__ Obuf, const int2* __restrict__ slot2,
    const float2* __restrict__ w2, const int* __restrict__ offs,
    float* __restrict__ out)
{
  const int t = blockIdx.x, tid = threadIdx.x;
  int2 s = slot2[t];
  float2 g = w2[t];
  int r0 = offs[s.x >> 12] + (s.x & 4095);
  int r1 = offs[s.y >> 12] + (s.y & 4095);
  const bf16* p0 = Obuf + (size_t)r0 * HH;
  const bf16* p1 = Obuf + (size_t)r1 * HH;
  float* po = out + (size_t)t * HH;
  int h = tid * 4;                         // 4 elems/thread, 8B bf16 reads, 16B fp32 write
  ushort4 a = *(const ushort4*)(p0 + h);
  ushort4 b = *(const ushort4*)(p1 + h);
  float4 o;
  o.x = g.x * __bfloat162float(*(bf16*)&a.x) + g.y * __bfloat162float(*(bf16*)&b.x);
  o.y = g.x * __bfloat162float(*(bf16*)&a.y) + g.y * __bfloat162float(*(bf16*)&b.y);
  o.z = g.x * __bfloat162float(*(bf16*)&a.z) + g.y * __bfloat162float(*(bf16*)&b.z);
  o.w = g.x * __bfloat162float(*(bf16*)&a.w) + g.y * __bfloat162float(*(bf16*)&b.w);
  *(float4*)(po + h) = o;
}

// ---------------- host ----------------
extern "C" void kernel_launch(void* const* d_in, const int* in_sizes, int n_in,
                              void* d_out, int out_size, void* d_ws, size_t ws_size,
                              hipStream_t stream)
{
  const float* x  = (const float*)d_in[0];
  const float* Wr = (const float*)d_in[1];
  const float* Wg = (const float*)d_in[2];
  const float* Wu = (const float*)d_in[3];
  const float* Wd = (const float*)d_in[4];
  float* out = (float*)d_out;
  char* ws = (char*)d_ws;

  // workspace layout (bytes): total ~75.9 MB
  int*    cnt      = (int*)(ws + 0);          // 8 ints (zeroed by prep rb0)
  int*    done     = (int*)(ws + 128);        // 1 int  (zeroed by prep rb0)
  int*    offs     = (int*)(ws + 256);        // 8 ints
  float*  impPart  = (float*)(ws + 512);      // 1024*8 floats (32 KB)
  int*    pair     = (int*)(ws + 33280);      // T ints (16 KB)
  float2* w2       = (float2*)(ws + 49664);   // T float2 (32 KB)
  int*    tok_list = (int*)(ws + 98304);      // E*T ints   (128 KB)
  int2*   slot2    = (int2*)(ws + 229376);    // T int2     (32 KB)
  bf16*   xb       = (bf16*)(ws + 360448);    // T*H bf16   (8 MB)
  bf16*   wgb      = (bf16*)(ws + 8749056);   // 16 MB [e][h][i] bf16 (UNtransposed)
  bf16*   wub      = (bf16*)(ws + 25526272);  // 16 MB [e][h][i]
  bf16*   wdb      = (bf16*)(ws + 42303488);  // 16 MB [e][i][h]
  bf16*   inter    = (bf16*)(ws + 59080704);  // 2T*I bf16  (16 MB, compact slots)
  // Obuf aliases wgb: wgb only read by gemm1 (completes before gemm2 writes);
  // prep rewrites wgb next replay.
  bf16*   Obuf     = wgb;

  prep_kernel<<<dim3(16, 8, 32), 256, 0, stream>>>(Wg, Wu, Wd, wgb, wub, wdb,
                                                   x, Wr, xb, pair, w2, impPart, cnt, done);
  scatter_kernel<<<16, 256, 0, stream>>>(pair, w2, cnt, tok_list, slot2,
                                         impPart, done, offs, out + (size_t)TT * HH);
  gemm1_kernel<<<dim3(16, 32, 8), 256, 0, stream>>>(xb, wgb, wub, cnt, offs, tok_list, inter);
  gemm2_kernel<<<dim3(8, 32, 8), 256, 0, stream>>>(inter, wdb, cnt, offs, Obuf);
  combine_kernel<<<TT, 256, 0, stream>>>(Obuf, slot2, w2, offs, out);
}

// Round 7
// 279.360 us; speedup vs baseline: 1.0415x; 1.0415x over previous
//
#include <hip/hip_runtime.h>
#include <hip/hip_bf16.h>
#include <math.h>

#define TT 4096   // tokens (B*S)
#define HH 1024   // hidden
#define EE 8      // experts
#define II 1024   // intermediate

typedef __bf16 bf16x8 __attribute__((ext_vector_type(8)));
typedef float  floatx4 __attribute__((ext_vector_type(4)));
typedef __hip_bfloat16 bf16;

// async global->LDS, 16B per lane. LDS dest is wave-uniform base + lane*16;
// global address is per-lane (gather allowed).
__device__ __forceinline__ void async_copy16(const void* g, void* s) {
  __builtin_amdgcn_global_load_lds((__attribute__((address_space(1))) void*)g,
                                   (__attribute__((address_space(3))) void*)s,
                                   16, 0, 0);
}

// R15: R5's B-swizzle fixed. Old swz(n)=n&7 gave 16-way ds_write conflicts
// (rows n=4bg+c: n&7 takes 2 values per wave; row stride 128B -> bank=chunk).
// New swz(n)=(n>>2)&7: write chunk = bo^(bg&7) spans all 8 slots (conflict-
// free); read becomes 2-way (free, m136). Same swz on write+read = bijective.
// Everything else identical to R5 (streaming-convert prep, reg-staged B with
// in-reg 8kx4n micro-transpose, double-buffered; separate combine).

// B-staging macros: bsrc = weight base + ibase (col offset), row stride 1024.
#define LOADB(v, kk) do { \
  _Pragma("unroll") \
  for (int j = 0; j < 8; j++) \
    v[j] = *(const uint2*)(bsrc + (size_t)((kk) + bo * 8 + j) * 1024); \
} while (0)

// component c of each ushort4 row -> one 16B LDS write (8 k-contig bf16)
#define STOREB(v) do { \
  _Pragma("unroll") \
  for (int c = 0; c < 4; c++) { \
    const int hs = (c & 1) * 16; \
    uint q0 = (c >> 1) ? v[0].y : v[0].x, q1 = (c >> 1) ? v[1].y : v[1].x; \
    uint q2 = (c >> 1) ? v[2].y : v[2].x, q3 = (c >> 1) ? v[3].y : v[3].x; \
    uint q4 = (c >> 1) ? v[4].y : v[4].x, q5 = (c >> 1) ? v[5].y : v[5].x; \
    uint q6 = (c >> 1) ? v[6].y : v[6].x, q7 = (c >> 1) ? v[7].y : v[7].x; \
    uint4 pk; \
    pk.x = ((q0 >> hs) & 0xffffu) | (((q1 >> hs) & 0xffffu) << 16); \
    pk.y = ((q2 >> hs) & 0xffffu) | (((q3 >> hs) & 0xffffu) << 16); \
    pk.z = ((q4 >> hs) & 0xffffu) | (((q5 >> hs) & 0xffffu) << 16); \
    pk.w = ((q6 >> hs) & 0xffffu) | (((q7 >> hs) & 0xffffu) << 16); \
    *(uint4*)(Bs + bw[c]) = pk; \
  } \
} while (0)

// ---------------- prep: convert-copy weights (z<24) | router (z>=24) ----------------
__global__ __launch_bounds__(256) void prep_kernel(
    const float* __restrict__ Wg, const float* __restrict__ Wu, const float* __restrict__ Wd,
    bf16* __restrict__ wgb, bf16* __restrict__ wub, bf16* __restrict__ wdb,
    const float* __restrict__ x, const float* __restrict__ Wr,
    bf16* __restrict__ xb, int* __restrict__ pair, float2* __restrict__ w2,
    float* __restrict__ impPart, int* __restrict__ cnt, int* __restrict__ done)
{
  const int tid = threadIdx.x;
  if (blockIdx.z < 24) {
    // ---- streaming fp32->bf16 convert, layout preserved ----
    const int zi = blockIdx.z >> 3, e = blockIdx.z & 7;
    const float* s = (zi == 0 ? Wg : zi == 1 ? Wu : Wd) + (size_t)e * 1024 * 1024;
    bf16* d = (zi == 0 ? wgb : zi == 1 ? wub : wdb) + (size_t)e * 1024 * 1024;
    const int base = (blockIdx.y * 16 + blockIdx.x) * 8192;
    #pragma unroll
    for (int i = 0; i < 8; i++) {
      int idx = base + tid * 4 + i * 1024;
      float4 v = *(const float4*)(s + idx);
      bf16 t4[4] = {__float2bfloat16(v.x), __float2bfloat16(v.y),
                    __float2bfloat16(v.z), __float2bfloat16(v.w)};
      *(float2*)(d + idx) = *(float2*)t4;     // 8B store
    }
  } else {
    // ---- router path: 1024 blocks (z=24..31, 128/plane), 4 tokens/block ----
    __shared__ float simp[8];
    const int rb = (blockIdx.z - 24) * 128 + blockIdx.y * 16 + blockIdx.x;
    if (tid < 8) simp[tid] = 0.f;
    if (rb == 0) {                                     // replaces hipMemsetAsync(cnt)
      if (tid < 8) cnt[tid] = 0;
      else if (tid == 8) *done = 0;
    }
    __syncthreads();

    const int w = tid >> 6, lane = tid & 63;
    const int t = rb * 4 + w;
    const float* xr = x + (size_t)t * HH;
    float acc[8] = {0.f,0.f,0.f,0.f,0.f,0.f,0.f,0.f};
    #pragma unroll
    for (int i = 0; i < 16; i++) {
      int h = lane + i * 64;
      float xv = xr[h];
      xb[(size_t)t * HH + h] = __float2bfloat16(xv);
      const float4* wr = (const float4*)(Wr + h * 8);
      float4 a = wr[0], b = wr[1];
      acc[0] += xv * a.x; acc[1] += xv * a.y; acc[2] += xv * a.z; acc[3] += xv * a.w;
      acc[4] += xv * b.x; acc[5] += xv * b.y; acc[6] += xv * b.z; acc[7] += xv * b.w;
    }
    #pragma unroll
    for (int e = 0; e < 8; e++) {
      #pragma unroll
      for (int off = 32; off > 0; off >>= 1)
        acc[e] += __shfl_xor(acc[e], off);
    }
    if (lane == 0) {
      int i0 = 0;
      #pragma unroll
      for (int e = 1; e < 8; e++) if (acc[e] > acc[i0]) i0 = e;   // lowest index wins ties
      int i1 = (i0 == 0) ? 1 : 0;
      #pragma unroll
      for (int e = 0; e < 8; e++) if (e != i0 && acc[e] > acc[i1]) i1 = e;
      float mx = acc[i0];
      float pe[8]; float s = 0.f;
      #pragma unroll
      for (int e = 0; e < 8; e++) { pe[e] = __expf(acc[e] - mx); s += pe[e]; }
      float inv = 1.f / s;
      #pragma unroll
      for (int e = 0; e < 8; e++) atomicAdd(simp + e, pe[e] * inv);   // LDS atomic
      float p0 = pe[i0] * inv, p1 = pe[i1] * inv;
      float wn2 = 1.f / (p0 + p1);
      pair[t] = i0 | (i1 << 8);
      w2[t] = make_float2(p0 * wn2, p1 * wn2);
    }
    __syncthreads();
    if (tid < 8) impPart[rb * 8 + tid] = simp[tid];
  }
}

// ---------------- scatter + fused finalize (last-block) ----------------
__global__ __launch_bounds__(256) void scatter_kernel(
    const int* __restrict__ pair, const float2* __restrict__ w2,
    int* __restrict__ cnt, int* __restrict__ tok_list, int2* __restrict__ slot2,
    const float* __restrict__ impPart, int* __restrict__ done,
    int* __restrict__ offs, float* __restrict__ aux_out)
{
  __shared__ int lcnt[8];
  __shared__ int lbase[8];
  __shared__ float part[256];
  __shared__ int scnt[8];
  __shared__ int lastFlag;
  const int tid = threadIdx.x;
  const int t = blockIdx.x * 256 + tid;
  if (tid < 8) lcnt[tid] = 0;
  __syncthreads();
  int pr = pair[t];
  int e0 = pr & 0xff, e1 = pr >> 8;
  int lp0 = atomicAdd(lcnt + e0, 1);
  int lp1 = atomicAdd(lcnt + e1, 1);
  __syncthreads();
  if (tid < 8) lbase[tid] = atomicAdd(cnt + tid, lcnt[tid]);   // 8 global atomics per block
  __syncthreads();
  int p0 = lbase[e0] + lp0, p1 = lbase[e1] + lp1;
  tok_list[e0 * TT + p0] = t;
  tok_list[e1 * TT + p1] = t;
  slot2[t] = make_int2((e0 << 12) | p0, (e1 << 12) | p1);

  // ---- fused finalize: last block reduces impPart, prefix offsets, aux ----
  __threadfence();
  __syncthreads();
  if (tid == 0) lastFlag = (atomicAdd(done, 1) == (int)gridDim.x - 1);
  __syncthreads();
  if (!lastFlag) return;
  __threadfence();                                   // acquire
  if (tid < 8) scnt[tid] = atomicAdd(cnt + tid, 0);  // coherent cross-XCD read
  const int e = tid & 7, r = tid >> 3;               // 32 chunks x 8 experts
  float s = 0.f;
  for (int i = r; i < 1024; i += 32) s += impPart[i * 8 + e];  // prep output: plain read OK
  part[tid] = s;
  __syncthreads();
  if (tid == 0) {
    float impf[8];
    #pragma unroll
    for (int e2 = 0; e2 < 8; e2++) {
      float ss = 0.f;
      #pragma unroll
      for (int j = 0; j < 32; j++) ss += part[j * 8 + e2];
      impf[e2] = ss;
    }
    int o = 0; float sl = 0.f;
    for (int e2 = 0; e2 < 8; e2++) { offs[e2] = o; o += scnt[e2]; sl += (float)scnt[e2] * impf[e2]; }
    aux_out[0] = (float)EE * 0.01f * sl / ((float)TT * (float)TT);
  }
}

// ---------------- gemm1: inter = silu(A@Wg) * (A@Wu); B staged w/ micro-transpose ----------------
// 128M x 128N tile over logical N=2048 interleave (n=(i>>4)*32+mat*16+(i&15)),
// BK=64; A via global_load_lds from xb; B: 8B row loads from UNtransposed
// wgb/wub + in-reg 8kx4n transpose + swizzled ds_write_b128 (swz=(n>>2)&7),
// double-buffered.
__global__ __launch_bounds__(256) void gemm1_kernel(
    const bf16* __restrict__ xb, const bf16* __restrict__ wgb, const bf16* __restrict__ wub,
    const int* __restrict__ cnt, const int* __restrict__ offs,
    const int* __restrict__ tok_list, bf16* __restrict__ inter)
{
  const int flat = blockIdx.x + 16 * (blockIdx.y + 32 * blockIdx.z);
  const int work = (flat & 7) * 512 + (flat >> 3);
  const int e = work >> 9;
  const int M = cnt[e];
  const int m0 = ((work >> 4) & 31) * 128;
  if (m0 >= M) return;
  const int n0 = (work & 15) * 128;
  const int off = offs[e];

  __shared__ alignas(16) bf16 As[128 * 64];   // 16 KB
  __shared__ alignas(16) bf16 Bs[128 * 64];   // 16 KB
  __shared__ int sTok[128];

  const int tid = threadIdx.x;
  if (tid < 128) {
    int p = m0 + tid;
    sTok[tid] = tok_list[e * TT + (p < M ? p : M - 1)];
  }

  const int w = tid >> 6, lane = tid & 63;
  const int quad = lane >> 4, l16 = lane & 15;
  const int srow = lane >> 3, schunk = lane & 7;   // A staging: 8 rows x 8 chunks/issue
  const int wm = (w & 1) * 64, wn = (w >> 1) * 64;

  // B-staging thread mapping: 32 n-groups of 4 x 8 k-octets
  const int bg = tid & 31, bo = tid >> 5;
  const int nl = bg * 4;
  const int nglob = n0 + nl;
  const int ibase = ((nglob >> 5) << 4) + (nglob & 15);      // source col in Wg/Wu
  const bf16* bsrc = (((nglob >> 4) & 1) ? wub : wgb) + (size_t)e * 1024 * 1024 + ibase;
  int bw[4];
  #pragma unroll
  for (int c = 0; c < 4; c++) {
    int n = nl + c;
    bw[c] = n * 64 + ((bo ^ (bg & 7)) << 3);   // swz(n)=(n>>2)&7 = bg&7: conflict-free write
  }

  floatx4 zero4 = {0.f, 0.f, 0.f, 0.f};
  floatx4 acc[4][4];
  #pragma unroll
  for (int mi = 0; mi < 4; mi++)
    #pragma unroll
    for (int ni = 0; ni < 4; ni++) acc[mi][ni] = zero4;

  __syncthreads();  // sTok visible

  // A staging: 16 issues, 4 per wave; k-invariant pointers
  const bf16* srcA[4]; bf16* dstA[4];
  #pragma unroll
  for (int i = 0; i < 4; i++) {
    int q = w + 4 * i, r = q * 8 + srow;
    int col = ((schunk ^ (r & 7)) << 3);
    srcA[i] = xb + (size_t)sTok[r] * HH + col;
    dstA[i] = As + q * 512;
  }
  // k-invariant swizzled LDS read offsets (A: swz=r&7; B: swz=(r>>2)&7)
  int offA[4][2], offB[4][2];
  #pragma unroll
  for (int mi = 0; mi < 4; mi++) {
    int r = wm + mi * 16 + l16;
    #pragma unroll
    for (int h = 0; h < 2; h++)
      offA[mi][h] = r * 64 + (((h * 4 + quad) ^ (r & 7)) << 3);
  }
  #pragma unroll
  for (int ni = 0; ni < 4; ni++) {
    int r = wn + ni * 16 + l16;
    #pragma unroll
    for (int h = 0; h < 2; h++)
      offB[ni][h] = r * 64 + (((h * 4 + quad) ^ ((r >> 2) & 7)) << 3);
  }

#define G1_MFMA() do { \
    bf16x8 af[4][2]; \
    _Pragma("unroll") \
    for (int mi = 0; mi < 4; mi++) { \
      af[mi][0] = *(const bf16x8*)(As + offA[mi][0]); \
      af[mi][1] = *(const bf16x8*)(As + offA[mi][1]); \
    } \
    _Pragma("unroll") \
    for (int ni = 0; ni < 4; ni++) { \
      bf16x8 b0 = *(const bf16x8*)(Bs + offB[ni][0]); \
      bf16x8 b1 = *(const bf16x8*)(Bs + offB[ni][1]); \
      _Pragma("unroll") \
      for (int mi = 0; mi < 4; mi++) { \
        acc[mi][ni] = __builtin_amdgcn_mfma_f32_16x16x32_bf16(af[mi][0], b0, acc[mi][ni], 0, 0, 0); \
        acc[mi][ni] = __builtin_amdgcn_mfma_f32_16x16x32_bf16(af[mi][1], b1, acc[mi][ni], 0, 0, 0); \
      } \
    } \
  } while (0)

  uint2 vA[8], vB[8];
  LOADB(vA, 0);
  for (int k0 = 0; k0 < HH; k0 += 128) {
    // step 0: consume vA, prefetch vB@k0+64
    if (k0) __syncthreads();
    #pragma unroll
    for (int i = 0; i < 4; i++) { async_copy16(srcA[i], dstA[i]); srcA[i] += 64; }
    STOREB(vA);
    LOADB(vB, k0 + 64);
    __syncthreads();
    G1_MFMA();
    // step 1: consume vB, prefetch vA@k0+128
    __syncthreads();
    #pragma unroll
    for (int i = 0; i < 4; i++) { async_copy16(srcA[i], dstA[i]); srcA[i] += 64; }
    STOREB(vB);
    if (k0 + 128 < HH) LOADB(vA, k0 + 128);
    __syncthreads();
    G1_MFMA();
  }

  // epilogue: pair frags (2*pr = g, 2*pr+1 = u); i = (n0+wn)/2 + pr*16 + l16
  #pragma unroll
  for (int mi = 0; mi < 4; mi++)
    #pragma unroll
    for (int pr = 0; pr < 2; pr++) {
      int icol = ((n0 + wn) >> 1) + pr * 16 + l16;
      #pragma unroll
      for (int r = 0; r < 4; r++) {
        int row = wm + mi * 16 + quad * 4 + r;
        int p = m0 + row;
        if (p < M) {
          float gv = acc[mi][2 * pr][r], uv = acc[mi][2 * pr + 1][r];
          float val = gv / (1.f + __expf(-gv)) * uv;
          inter[(size_t)(off + p) * II + icol] = __float2bfloat16(val);
        }
      }
    }
}

// ---------------- gemm2: Obuf[slot] = inter @ Wd; B staged w/ micro-transpose ----------------
// B[n=h][k=i] = Wd[e][i][h] (untransposed): same reg-staging as gemm1, direct n map.
__global__ __launch_bounds__(256) void gemm2_kernel(
    const bf16* __restrict__ inter, const bf16* __restrict__ wdb,
    const int* __restrict__ cnt, const int* __restrict__ offs,
    bf16* __restrict__ Obuf)
{
  const int flat = blockIdx.x + 8 * (blockIdx.y + 32 * blockIdx.z);
  const int work = (flat & 7) * 256 + (flat >> 3);
  const int e = work >> 8;
  const int M = cnt[e];
  const int m0 = ((work >> 3) & 31) * 128;
  if (m0 >= M) return;
  const int n0 = (work & 7) * 128;
  const int off = offs[e];

  __shared__ alignas(16) bf16 As[128 * 64];   // 16 KB
  __shared__ alignas(16) bf16 Bs[128 * 64];   // 16 KB

  const int tid = threadIdx.x;
  const int w = tid >> 6, lane = tid & 63;
  const int quad = lane >> 4, l16 = lane & 15;
  const int srow = lane >> 3, schunk = lane & 7;
  const int wm = (w & 1) * 64, wn = (w >> 1) * 64;

  const int bg = tid & 31, bo = tid >> 5;
  const int nl = bg * 4;
  const bf16* bsrc = wdb + (size_t)e * 1024 * 1024 + (n0 + nl);
  int bw[4];
  #pragma unroll
  for (int c = 0; c < 4; c++) {
    int n = nl + c;
    bw[c] = n * 64 + ((bo ^ (bg & 7)) << 3);   // swz(n)=(n>>2)&7 = bg&7
  }

  floatx4 zero4 = {0.f, 0.f, 0.f, 0.f};
  floatx4 acc[4][4];
  #pragma unroll
  for (int mi = 0; mi < 4; mi++)
    #pragma unroll
    for (int ni = 0; ni < 4; ni++) acc[mi][ni] = zero4;

  // A staging: 16 issues, 4 per wave
  const bf16* srcA[4]; bf16* dstA[4];
  #pragma unroll
  for (int i = 0; i < 4; i++) {
    int q = w + 4 * i, r = q * 8 + srow;
    int col = ((schunk ^ (r & 7)) << 3);
    int p = m0 + r; int pc = p < M ? p : M - 1;
    srcA[i] = inter + (size_t)(off + pc) * II + col;
    dstA[i] = As + q * 512;
  }
  int offA[4][2], offB[4][2];
  #pragma unroll
  for (int mi = 0; mi < 4; mi++) {
    int r = wm + mi * 16 + l16;
    #pragma unroll
    for (int h = 0; h < 2; h++)
      offA[mi][h] = r * 64 + (((h * 4 + quad) ^ (r & 7)) << 3);
  }
  #pragma unroll
  for (int ni = 0; ni < 4; ni++) {
    int r = wn + ni * 16 + l16;
    #pragma unroll
    for (int h = 0; h < 2; h++)
      offB[ni][h] = r * 64 + (((h * 4 + quad) ^ ((r >> 2) & 7)) << 3);
  }

  uint2 vA[8], vB[8];
  LOADB(vA, 0);
  for (int k0 = 0; k0 < II; k0 += 128) {
    if (k0) __syncthreads();
    #pragma unroll
    for (int i = 0; i < 4; i++) { async_copy16(srcA[i], dstA[i]); srcA[i] += 64; }
    STOREB(vA);
    LOADB(vB, k0 + 64);
    __syncthreads();
    G1_MFMA();
    __syncthreads();
    #pragma unroll
    for (int i = 0; i < 4; i++) { async_copy16(srcA[i], dstA[i]); srcA[i] += 64; }
    STOREB(vB);
    if (k0 + 128 < II) LOADB(vA, k0 + 128);
    __syncthreads();
    G1_MFMA();
  }

  #pragma unroll
  for (int mi = 0; mi < 4; mi++)
    #pragma unroll
    for (int ni = 0; ni < 4; ni++) {
      #pragma unroll
      for (int r = 0; r < 4; r++) {
        int row = wm + mi * 16 + quad * 4 + r;
        int p = m0 + row;
        if (p < M)
          Obuf[(size_t)(off + p) * HH + (n0 + wn + ni * 16 + l16)] = __float2bfloat16(acc[mi][ni][r]);
      }
    }
}

// ---------------- combine: out[t] = g0*Obuf[slot0] + g1*Obuf[slot1] ----------------
__global__ __launch_bounds__(256) void combine_kernel(
    const bf16* __restrict__ Obuf, const int2* __restrict__ slot2,
    const float2* __restrict__ w2, const int* __restrict__ offs,
    float* __restrict__ out)
{
  const int t = blockIdx.x, tid = threadIdx.x;
  int2 s = slot2[t];
  float2 g = w2[t];
  int r0 = offs[s.x >> 12] + (s.x & 4095);
  int r1 = offs[s.y >> 12] + (s.y & 4095);
  const bf16* p0 = Obuf + (size_t)r0 * HH;
  const bf16* p1 = Obuf + (size_t)r1 * HH;
  float* po = out + (size_t)t * HH;
  int h = tid * 4;                         // 4 elems/thread, 8B bf16 reads, 16B fp32 write
  ushort4 a = *(const ushort4*)(p0 + h);
  ushort4 b = *(const ushort4*)(p1 + h);
  float4 o;
  o.x = g.x * __bfloat162float(*(bf16*)&a.x) + g.y * __bfloat162float(*(bf16*)&b.x);
  o.y = g.x * __bfloat162float(*(bf16*)&a.y) + g.y * __bfloat162float(*(bf16*)&b.y);
  o.z = g.x * __bfloat162float(*(bf16*)&a.z) + g.y * __bfloat162float(*(bf16*)&b.z);
  o.w = g.x * __bfloat162float(*(bf16*)&a.w) + g.y * __bfloat162float(*(bf16*)&b.w);
  *(float4*)(po + h) = o;
}

// ---------------- host ----------------
extern "C" void kernel_launch(void* const* d_in, const int* in_sizes, int n_in,
                              void* d_out, int out_size, void* d_ws, size_t ws_size,
                              hipStream_t stream)
{
  const float* x  = (const float*)d_in[0];
  const float* Wr = (const float*)d_in[1];
  const float* Wg = (const float*)d_in[2];
  const float* Wu = (const float*)d_in[3];
  const float* Wd = (const float*)d_in[4];
  float* out = (float*)d_out;
  char* ws = (char*)d_ws;

  // workspace layout (bytes): total ~75.9 MB
  int*    cnt      = (int*)(ws + 0);          // 8 ints (zeroed by prep rb0)
  int*    done     = (int*)(ws + 128);        // 1 int  (zeroed by prep rb0)
  int*    offs     = (int*)(ws + 256);        // 8 ints
  float*  impPart  = (float*)(ws + 512);      // 1024*8 floats (32 KB)
  int*    pair     = (int*)(ws + 33280);      // T ints (16 KB)
  float2* w2       = (float2*)(ws + 49664);   // T float2 (32 KB)
  int*    tok_list = (int*)(ws + 98304);      // E*T ints   (128 KB)
  int2*   slot2    = (int2*)(ws + 229376);    // T int2     (32 KB)
  bf16*   xb       = (bf16*)(ws + 360448);    // T*H bf16   (8 MB)
  bf16*   wgb      = (bf16*)(ws + 8749056);   // 16 MB [e][h][i] bf16 (UNtransposed)
  bf16*   wub      = (bf16*)(ws + 25526272);  // 16 MB [e][h][i]
  bf16*   wdb      = (bf16*)(ws + 42303488);  // 16 MB [e][i][h]
  bf16*   inter    = (bf16*)(ws + 59080704);  // 2T*I bf16  (16 MB, compact slots)
  // Obuf aliases wgb: wgb only read by gemm1 (completes before gemm2 writes);
  // prep rewrites wgb next replay.
  bf16*   Obuf     = wgb;

  prep_kernel<<<dim3(16, 8, 32), 256, 0, stream>>>(Wg, Wu, Wd, wgb, wub, wdb,
                                                   x, Wr, xb, pair, w2, impPart, cnt, done);
  scatter_kernel<<<16, 256, 0, stream>>>(pair, w2, cnt, tok_list, slot2,
                                         impPart, done, offs, out + (size_t)TT * HH);
  gemm1_kernel<<<dim3(16, 32, 8), 256, 0, stream>>>(xb, wgb, wub, cnt, offs, tok_list, inter);
  gemm2_kernel<<<dim3(8, 32, 8), 256, 0, stream>>>(inter, wdb, cnt, offs, Obuf);
  combine_kernel<<<TT, 256, 0, stream>>>(Obuf, slot2, w2, offs, out);
}